// Round 1
// baseline (4745.994 us; speedup 1.0000x reference)
//
#include <hip/hip_runtime.h>
#include <math.h>

// Shapes
#define BB 8
#define NN 4096          // 64*64
#define CC 512
#define TT 77
#define HHH 8
#define DHH 64
#define MTOT 32768       // B*N

__device__ __forceinline__ float wred_sum(float v) {
#pragma unroll
  for (int o = 32; o >= 1; o >>= 1) v += __shfl_xor(v, o, 64);
  return v;
}

// ---------------- LayerNorm over rows of 512 (one wave per row) ----------------
__global__ __launch_bounds__(256)
void ln_kernel(const float* __restrict__ in, const float* __restrict__ gw,
               const float* __restrict__ gb, float* __restrict__ out) {
  const int wv = threadIdx.x >> 6, lane = threadIdx.x & 63;
  const size_t row = (size_t)blockIdx.x * 4 + wv;
  const float* p = in + row * 512 + lane * 8;
  float4 a = *(const float4*)p;
  float4 b = *(const float4*)(p + 4);
  float s = a.x + a.y + a.z + a.w + b.x + b.y + b.z + b.w;
  float mu = wred_sum(s) * (1.0f / 512.0f);
  float d[8] = {a.x - mu, a.y - mu, a.z - mu, a.w - mu,
                b.x - mu, b.y - mu, b.z - mu, b.w - mu};
  float ss = 0.f;
#pragma unroll
  for (int i = 0; i < 8; ++i) ss = fmaf(d[i], d[i], ss);
  float var = wred_sum(ss) * (1.0f / 512.0f);
  float rstd = rsqrtf(var + 1e-5f);
  float4 w0 = *(const float4*)(gw + lane * 8);
  float4 w1 = *(const float4*)(gw + lane * 8 + 4);
  float4 c0 = *(const float4*)(gb + lane * 8);
  float4 c1 = *(const float4*)(gb + lane * 8 + 4);
  float4 o0, o1;
  o0.x = d[0] * rstd * w0.x + c0.x;
  o0.y = d[1] * rstd * w0.y + c0.y;
  o0.z = d[2] * rstd * w0.z + c0.z;
  o0.w = d[3] * rstd * w0.w + c0.w;
  o1.x = d[4] * rstd * w1.x + c1.x;
  o1.y = d[5] * rstd * w1.y + c1.y;
  o1.z = d[6] * rstd * w1.z + c1.z;
  o1.w = d[7] * rstd * w1.w + c1.w;
  float* q = out + row * 512 + lane * 8;
  *(float4*)q = o0;
  *(float4*)(q + 4) = o1;
}

// ---------------- row-wise L2 normalize over 512, in place ----------------
__global__ __launch_bounds__(256)
void l2norm_kernel(float* __restrict__ x) {
  const int wv = threadIdx.x >> 6, lane = threadIdx.x & 63;
  const size_t row = (size_t)blockIdx.x * 4 + wv;
  float* p = x + row * 512 + lane * 8;
  float4 a = *(const float4*)p;
  float4 b = *(const float4*)(p + 4);
  float ss = a.x * a.x + a.y * a.y + a.z * a.z + a.w * a.w +
             b.x * b.x + b.y * b.y + b.z * b.z + b.w * b.w;
  ss = wred_sum(ss);
  float sc = 1.0f / fmaxf(sqrtf(ss), 1e-6f);
  a.x *= sc; a.y *= sc; a.z *= sc; a.w *= sc;
  b.x *= sc; b.y *= sc; b.z *= sc; b.w *= sc;
  *(float4*)p = a;
  *(float4*)(p + 4) = b;
}

// ---------------- text projections: k (l2-normed), v, pad mask ----------------
// one block per text token row (B*T = 616)
__global__ __launch_bounds__(256)
void text_proj_kernel(const float* __restrict__ text,
                      const float* __restrict__ wk, const float* __restrict__ bk,
                      const float* __restrict__ wv, const float* __restrict__ bv,
                      float* __restrict__ kf, float* __restrict__ vf,
                      float* __restrict__ pad) {
  __shared__ float st[512];
  __shared__ float red[8];
  const int tid = threadIdx.x;
  const int row = blockIdx.x;
  const int wvid = tid >> 6, lane = tid & 63;
  float t0 = text[(size_t)row * 512 + tid];
  float t1 = text[(size_t)row * 512 + tid + 256];
  st[tid] = t0;
  st[tid + 256] = t1;
  float ab = wred_sum(fabsf(t0) + fabsf(t1));
  if (lane == 0) red[wvid] = ab;
  __syncthreads();
  const int c0 = tid, c1 = tid + 256;
  float ak0 = bk[c0], ak1 = bk[c1];
  float av0 = bv[c0], av1 = bv[c1];
  for (int kk = 0; kk < 512; ++kk) {
    float tv = st[kk];
    ak0 = fmaf(tv, wk[(size_t)kk * 512 + c0], ak0);
    ak1 = fmaf(tv, wk[(size_t)kk * 512 + c1], ak1);
    av0 = fmaf(tv, wv[(size_t)kk * 512 + c0], av0);
    av1 = fmaf(tv, wv[(size_t)kk * 512 + c1], av1);
  }
  float ss = wred_sum(ak0 * ak0 + ak1 * ak1);
  if (lane == 0) red[4 + wvid] = ss;
  __syncthreads();
  float padsum = red[0] + red[1] + red[2] + red[3];
  float sstot = red[4] + red[5] + red[6] + red[7];
  float sc = 1.0f / fmaxf(sqrtf(sstot), 1e-6f);
  kf[(size_t)row * 512 + c0] = ak0 * sc;
  kf[(size_t)row * 512 + c1] = ak1 * sc;
  vf[(size_t)row * 512 + c0] = av0;
  vf[(size_t)row * 512 + c1] = av1;
  if (tid == 0) pad[row] = (padsum <= 1e-6f) ? 1.0f : 0.0f;
}

// ---------------- fused attention: sims -> top3 -> softmax -> conf -> PV -------
__device__ __forceinline__ void top3_insert(float v, float& a, float& b, float& c) {
  if (v > a) { c = b; b = a; a = v; }
  else if (v > b) { c = b; b = v; }
  else if (v > c) { c = v; }
}

__global__ __launch_bounds__(256)
void attn_kernel(const float* __restrict__ q,      // [32768,512] l2-normed
                 const float* __restrict__ kf,     // [616,512] l2-normed
                 const float* __restrict__ vf,     // [616,512]
                 const float* __restrict__ pad,    // [616] 1.0 if padded
                 const float* __restrict__ logit_scale,
                 float* __restrict__ aligned,      // [32768,512]
                 float* __restrict__ conf_out) {   // [32768]
  __shared__ __align__(16) float s_q[512];
  __shared__ float s_sim[8][80];
  __shared__ float s_attn[8][80];
  __shared__ float s_conf[8];
  const int tid = threadIdx.x;
  const int row = blockIdx.x;
  const int b = row >> 12;
  float ls = fminf(fmaxf(logit_scale[0], -2.0f), 2.0f);
  const float scale = expf(ls) * 0.125f;  // / sqrt(64)
  s_q[tid] = q[(size_t)row * 512 + tid];
  s_q[tid + 256] = q[(size_t)row * 512 + tid + 256];
  __syncthreads();
  // sims for 8*77 = 616 (h,t) pairs
  for (int p = tid; p < 616; p += 256) {
    const int h = p / 77;
    const int t = p - h * 77;
    float sim;
    if (pad[b * 77 + t] != 0.0f) {
      sim = -INFINITY;
    } else {
      const float* kp = kf + (size_t)(b * 77 + t) * 512 + h * 64;
      const float4* q4 = (const float4*)(s_q + h * 64);
      float acc = 0.f;
#pragma unroll
      for (int d4 = 0; d4 < 16; ++d4) {
        float4 kk = *(const float4*)(kp + d4 * 4);
        float4 qq = q4[d4];
        acc = fmaf(qq.x, kk.x, acc);
        acc = fmaf(qq.y, kk.y, acc);
        acc = fmaf(qq.z, kk.z, acc);
        acc = fmaf(qq.w, kk.w, acc);
      }
      sim = acc * scale;
    }
    s_sim[h][t] = sim;
  }
  __syncthreads();
  const int wv = tid >> 6, lane = tid & 63;
  for (int hh = 0; hh < 2; ++hh) {
    const int h = wv * 2 + hh;
    const float v0 = s_sim[h][lane];
    const float v1 = (lane < 13) ? s_sim[h][lane + 64] : -INFINITY;
    // lane-local top3 then butterfly merge (tie-exact: duplicates fill slots)
    float a = -INFINITY, bt = -INFINITY, c = -INFINITY;
    top3_insert(v0, a, bt, c);
    top3_insert(v1, a, bt, c);
#pragma unroll
    for (int s = 32; s >= 1; s >>= 1) {
      float oa = __shfl_xor(a, s, 64);
      float ob = __shfl_xor(bt, s, 64);
      float oc = __shfl_xor(c, s, 64);
      top3_insert(oa, a, bt, c);
      top3_insert(ob, a, bt, c);
      top3_insert(oc, a, bt, c);
    }
    const float thr = c, m1 = a;
    float ev0 = 0.f, ev1 = 0.f;
    float s0 = 0.f, s1 = 0.f, cnt = 0.f;
    if (v0 >= thr) {
      float e = expf(v0 - m1);
      if (e > 0.f) { ev0 = e; s0 += e; s1 += e * (v0 - m1); cnt += 1.f; }
    }
    if (v1 >= thr) {
      float e = expf(v1 - m1);
      if (e > 0.f) { ev1 = e; s0 += e; s1 += e * (v1 - m1); cnt += 1.f; }
    }
    s0 = wred_sum(s0);
    s1 = wred_sum(s1);
    cnt = wred_sum(cnt);
    float attn0 = 0.f, attn1 = 0.f, conf_h = 0.f;
    if (cnt > 0.f) {
      const float inv = 1.0f / s0;
      attn0 = ev0 * inv;
      attn1 = ev1 * inv;
      const float maxp = inv;  // exp(0)/S
      const float teff = fmaxf(cnt, 2.0f);
      // H = ln(S) - s1/S ; plus clamped contributions of ~zero probs
      float entn = (logf(s0) - s1 * inv) + (77.0f - cnt) * 1.8420681e-7f;
      const float ent = fmaxf(entn / logf(teff), 0.0f);
      conf_h = fminf(fmaxf(maxp * (1.0f - ent), 0.0f), 1.0f);
    }
    s_attn[h][lane] = attn0;
    if (lane < 13) s_attn[h][lane + 64] = attn1;
    if (lane == 0) s_conf[h] = conf_h;
  }
  __syncthreads();
  if (tid == 0) {
    float cm = 0.f;
#pragma unroll
    for (int h = 0; h < 8; ++h) cm += s_conf[h];
    cm *= 0.125f;
    cm = fminf(fmaxf(cm, 0.0f), 1.0f);
    conf_out[row] = 0.35f + 0.65f * cm;
  }
  // PV: sparse (<= ~3 nonzero weights per head)
  for (int c0 = tid; c0 < 512; c0 += 256) {
    const int h = c0 >> 6;
    float acc = 0.f;
    for (int t = 0; t < 77; ++t) {
      const float w = s_attn[h][t];
      if (w != 0.0f) acc = fmaf(w, vf[(size_t)(b * 77 + t) * 512 + c0], acc);
    }
    aligned[(size_t)row * 512 + c0] = acc;
  }
}

// ---------------- tiled fp32 GEMM: out = epilogue(A[M,K] @ W[K,N] + bias) ------
// EPI 0: +bias                       (q projection)
// EPI 1: (.)*e0[row]                 (wo, conf scale)
// EPI 2: e0[row,col] + alpha*sigmoid(.)*clip(e2[row],.3,1)*e1[row,col]  (gate+residual -> y)
// EPI 3: gelu(.) exact               (ffn1)
// EPI 4: e0[row,col] + .             (ffn2 + residual y)
template <int EPI>
__global__ __launch_bounds__(256)
void gemm_kernel(const float* __restrict__ A, const float* __restrict__ Wt,
                 const float* __restrict__ bias, float* __restrict__ out,
                 int M, int N, int K,
                 const float* __restrict__ e0, const float* __restrict__ e1,
                 const float* __restrict__ e2, const float* __restrict__ sc) {
  __shared__ float As[16][128];  // transposed A tile: As[k][m]
  __shared__ float Bs[16][128];  // Bs[k][n]
  const int tid = threadIdx.x;
  const int tx = tid & 15, ty = tid >> 4;
  const int row0 = blockIdx.y * 128, col0 = blockIdx.x * 128;
  float acc[8][8];
#pragma unroll
  for (int i = 0; i < 8; ++i)
#pragma unroll
    for (int j = 0; j < 8; ++j) acc[i][j] = 0.f;

  const int ar0 = tid >> 2, ac0 = (tid & 3) << 2;
  const int ar1 = ar0 + 64;
  const int br0 = tid >> 5, bc0 = (tid & 31) << 2;
  const int br1 = br0 + 8;
  const float* Ar0 = A + (size_t)(row0 + ar0) * K;
  const float* Ar1 = A + (size_t)(row0 + ar1) * K;

  for (int k0 = 0; k0 < K; k0 += 16) {
    float4 a0 = *(const float4*)(Ar0 + k0 + ac0);
    float4 a1 = *(const float4*)(Ar1 + k0 + ac0);
    float4 b0 = *(const float4*)(Wt + (size_t)(k0 + br0) * N + col0 + bc0);
    float4 b1 = *(const float4*)(Wt + (size_t)(k0 + br1) * N + col0 + bc0);
    __syncthreads();
    As[ac0 + 0][ar0] = a0.x; As[ac0 + 1][ar0] = a0.y;
    As[ac0 + 2][ar0] = a0.z; As[ac0 + 3][ar0] = a0.w;
    As[ac0 + 0][ar1] = a1.x; As[ac0 + 1][ar1] = a1.y;
    As[ac0 + 2][ar1] = a1.z; As[ac0 + 3][ar1] = a1.w;
    *(float4*)&Bs[br0][bc0] = b0;
    *(float4*)&Bs[br1][bc0] = b1;
    __syncthreads();
#pragma unroll
    for (int kk = 0; kk < 16; ++kk) {
      float av[8], bv[8];
      *(float4*)&av[0] = *(const float4*)&As[kk][ty * 8];
      *(float4*)&av[4] = *(const float4*)&As[kk][ty * 8 + 4];
      *(float4*)&bv[0] = *(const float4*)&Bs[kk][tx * 8];
      *(float4*)&bv[4] = *(const float4*)&Bs[kk][tx * 8 + 4];
#pragma unroll
      for (int i = 0; i < 8; ++i)
#pragma unroll
        for (int j = 0; j < 8; ++j) acc[i][j] = fmaf(av[i], bv[j], acc[i][j]);
    }
  }

  const int cb = col0 + tx * 8;
  float bb[8];
  *(float4*)&bb[0] = *(const float4*)(bias + cb);
  *(float4*)&bb[4] = *(const float4*)(bias + cb + 4);
  float alpha = 0.f;
  if (EPI == 2) alpha = sc[0];
#pragma unroll
  for (int i = 0; i < 8; ++i) {
    const int r = row0 + ty * 8 + i;
    float o[8];
#pragma unroll
    for (int j = 0; j < 8; ++j) o[j] = acc[i][j] + bb[j];
    if (EPI == 1) {
      const float cs = e0[r];
#pragma unroll
      for (int j = 0; j < 8; ++j) o[j] *= cs;
    } else if (EPI == 2) {
      const float g = fminf(fmaxf(e2[r], 0.3f), 1.0f);
      float xv[8], av2[8];
      *(float4*)&xv[0] = *(const float4*)(e0 + (size_t)r * N + cb);
      *(float4*)&xv[4] = *(const float4*)(e0 + (size_t)r * N + cb + 4);
      *(float4*)&av2[0] = *(const float4*)(e1 + (size_t)r * N + cb);
      *(float4*)&av2[4] = *(const float4*)(e1 + (size_t)r * N + cb + 4);
#pragma unroll
      for (int j = 0; j < 8; ++j) {
        const float sg = 1.0f / (1.0f + expf(-o[j]));
        o[j] = xv[j] + alpha * sg * g * av2[j];
      }
    } else if (EPI == 3) {
#pragma unroll
      for (int j = 0; j < 8; ++j)
        o[j] = 0.5f * o[j] * (1.0f + erff(o[j] * 0.70710678118654752f));
    } else if (EPI == 4) {
      float rv[8];
      *(float4*)&rv[0] = *(const float4*)(e0 + (size_t)r * N + cb);
      *(float4*)&rv[4] = *(const float4*)(e0 + (size_t)r * N + cb + 4);
#pragma unroll
      for (int j = 0; j < 8; ++j) o[j] += rv[j];
    }
    float* po = out + (size_t)r * N + cb;
    *(float4*)po = *(float4*)&o[0];
    *(float4*)(po + 4) = *(float4*)&o[4];
  }
}

extern "C" void kernel_launch(void* const* d_in, const int* in_sizes, int n_in,
                              void* d_out, int out_size, void* d_ws, size_t ws_size,
                              hipStream_t stream) {
  const float* visual = (const float*)d_in[0];
  const float* text   = (const float*)d_in[1];
  const float* geo    = (const float*)d_in[2];
  const float* ln1_w  = (const float*)d_in[3];
  const float* ln1_b  = (const float*)d_in[4];
  const float* wq     = (const float*)d_in[5];
  const float* bq     = (const float*)d_in[6];
  const float* wk     = (const float*)d_in[7];
  const float* bk     = (const float*)d_in[8];
  const float* wv     = (const float*)d_in[9];
  const float* bv     = (const float*)d_in[10];
  const float* wo     = (const float*)d_in[11];
  const float* bo     = (const float*)d_in[12];
  const float* gate_w = (const float*)d_in[13];
  const float* gate_b = (const float*)d_in[14];
  const float* logit_scale = (const float*)d_in[15];
  const float* alpha  = (const float*)d_in[16];
  const float* ln2_w  = (const float*)d_in[17];
  const float* ln2_b  = (const float*)d_in[18];
  const float* ffn_w1 = (const float*)d_in[19];
  const float* ffn_b1 = (const float*)d_in[20];
  const float* ffn_w2 = (const float*)d_in[21];
  const float* ffn_b2 = (const float*)d_in[22];
  float* out = (float*)d_out;

  float* W = (float*)d_ws;
  float* X    = W;                        // [32768,512] x -> (after LN2) h
  float* BUF1 = W + (size_t)16777216;     // qf -> alignedo -> y
  float* BUF2 = W + (size_t)33554432;     // aligned -> y/h ping-pong
  float* GCH  = W + (size_t)50331648;     // [4096,2048] gelu chunk
  float* KF   = GCH + (size_t)8388608;    // [616,512]
  float* VF   = KF + 315392;              // [616,512]
  float* PAD  = VF + 315392;              // [616]
  float* CONF = PAD + 616;                // [32768]

  // 1. x = LN1(visual)
  ln_kernel<<<MTOT / 4, 256, 0, stream>>>(visual, ln1_w, ln1_b, X);
  // 2. k (l2-normed), v, pad mask
  text_proj_kernel<<<BB * TT, 256, 0, stream>>>(text, wk, bk, wv, bv, KF, VF, PAD);
  // 3. q = x @ wq + bq
  dim3 g512(512 / 128, MTOT / 128);
  gemm_kernel<0><<<g512, 256, 0, stream>>>(X, wq, bq, BUF1, MTOT, 512, 512,
                                           nullptr, nullptr, nullptr, nullptr);
  // 4. q <- l2norm rows
  l2norm_kernel<<<MTOT / 4, 256, 0, stream>>>(BUF1);
  // 5. attention -> aligned (BUF2), conf_scale (CONF)
  attn_kernel<<<MTOT, 256, 0, stream>>>(BUF1, KF, VF, PAD, logit_scale, BUF2, CONF);
  // 6. alignedo = (aligned @ wo + bo) * conf  -> BUF1
  gemm_kernel<1><<<g512, 256, 0, stream>>>(BUF2, wo, bo, BUF1, MTOT, 512, 512,
                                           CONF, nullptr, nullptr, nullptr);
  // 7. y = x + alpha * sigmoid(x@gate_w+gate_b) * geo * alignedo  -> BUF2
  gemm_kernel<2><<<g512, 256, 0, stream>>>(X, gate_w, gate_b, BUF2, MTOT, 512, 512,
                                           X, BUF1, geo, alpha);
  // 8. h = LN2(y) -> X
  ln_kernel<<<MTOT / 4, 256, 0, stream>>>(BUF2, ln2_w, ln2_b, X);
  // 9. FFN chunked over M (8 chunks of 4096 rows)
  dim3 gf1(2048 / 128, 4096 / 128);
  dim3 gf2(512 / 128, 4096 / 128);
  for (int ch = 0; ch < 8; ++ch) {
    const size_t off = (size_t)ch * 4096;
    gemm_kernel<3><<<gf1, 256, 0, stream>>>(X + off * 512, ffn_w1, ffn_b1, GCH,
                                            4096, 2048, 512,
                                            nullptr, nullptr, nullptr, nullptr);
    gemm_kernel<4><<<gf2, 256, 0, stream>>>(GCH, ffn_w2, ffn_b2, out + off * 512,
                                            4096, 512, 2048,
                                            BUF2 + off * 512, nullptr, nullptr, nullptr);
  }
}

// Round 2
// 1383.797 us; speedup vs baseline: 3.4297x; 3.4297x over previous
//
#include <hip/hip_runtime.h>
#include <hip/hip_bf16.h>
#include <math.h>

#define TT 77
#define MTOT 32768

typedef __attribute__((ext_vector_type(8))) short bf16x8;
typedef __attribute__((ext_vector_type(4))) float floatx4;

#define GPTR(p) ((const __attribute__((address_space(1))) void*)(p))
#define LPTR(p) ((__attribute__((address_space(3))) void*)(p))

__device__ __forceinline__ float wred_sum(float v) {
#pragma unroll
  for (int o = 32; o >= 1; o >>= 1) v += __shfl_xor(v, o, 64);
  return v;
}

__device__ __forceinline__ unsigned short f2bf(float f) {
  unsigned int u = __float_as_uint(f);
  unsigned int r = (u + 0x7fffu + ((u >> 16) & 1u)) >> 16;
  return (unsigned short)r;
}
__device__ __forceinline__ float bf2f(unsigned short h) {
  return __uint_as_float(((unsigned int)h) << 16);
}

// ---------------- LayerNorm over rows of 512 -> bf16 out (one wave/row) -------
__global__ __launch_bounds__(256)
void ln_bf16_kernel(const float* __restrict__ in, const float* __restrict__ gw,
                    const float* __restrict__ gb, unsigned short* __restrict__ out) {
  const int wv = threadIdx.x >> 6, lane = threadIdx.x & 63;
  const size_t row = (size_t)blockIdx.x * 4 + wv;
  const float* p = in + row * 512 + lane * 8;
  float4 a = *(const float4*)p;
  float4 b = *(const float4*)(p + 4);
  float s = a.x + a.y + a.z + a.w + b.x + b.y + b.z + b.w;
  float mu = wred_sum(s) * (1.0f / 512.0f);
  float d[8] = {a.x - mu, a.y - mu, a.z - mu, a.w - mu,
                b.x - mu, b.y - mu, b.z - mu, b.w - mu};
  float ss = 0.f;
#pragma unroll
  for (int i = 0; i < 8; ++i) ss = fmaf(d[i], d[i], ss);
  float var = wred_sum(ss) * (1.0f / 512.0f);
  float rstd = rsqrtf(var + 1e-5f);
  float4 w0 = *(const float4*)(gw + lane * 8);
  float4 w1 = *(const float4*)(gw + lane * 8 + 4);
  float4 c0 = *(const float4*)(gb + lane * 8);
  float4 c1 = *(const float4*)(gb + lane * 8 + 4);
  float o[8];
  o[0] = d[0] * rstd * w0.x + c0.x;  o[1] = d[1] * rstd * w0.y + c0.y;
  o[2] = d[2] * rstd * w0.z + c0.z;  o[3] = d[3] * rstd * w0.w + c0.w;
  o[4] = d[4] * rstd * w1.x + c1.x;  o[5] = d[5] * rstd * w1.y + c1.y;
  o[6] = d[6] * rstd * w1.z + c1.z;  o[7] = d[7] * rstd * w1.w + c1.w;
  __align__(16) unsigned short ob[8];
#pragma unroll
  for (int i = 0; i < 8; ++i) ob[i] = f2bf(o[i]);
  *(uint4*)(out + row * 512 + lane * 8) = *(const uint4*)ob;
}

// ---------------- row-wise L2 normalize over 512, in place (fp32) -------------
__global__ __launch_bounds__(256)
void l2norm_kernel(float* __restrict__ x) {
  const int wv = threadIdx.x >> 6, lane = threadIdx.x & 63;
  const size_t row = (size_t)blockIdx.x * 4 + wv;
  float* p = x + row * 512 + lane * 8;
  float4 a = *(const float4*)p;
  float4 b = *(const float4*)(p + 4);
  float ss = a.x * a.x + a.y * a.y + a.z * a.z + a.w * a.w +
             b.x * b.x + b.y * b.y + b.z * b.z + b.w * b.w;
  ss = wred_sum(ss);
  float sc = 1.0f / fmaxf(sqrtf(ss), 1e-6f);
  a.x *= sc; a.y *= sc; a.z *= sc; a.w *= sc;
  b.x *= sc; b.y *= sc; b.z *= sc; b.w *= sc;
  *(float4*)p = a;
  *(float4*)(p + 4) = b;
}

// ---------------- weight transpose + bf16 convert: W[K,N] -> WT[N,K] ----------
__global__ __launch_bounds__(256)
void transpose_bf16_kernel(const float* __restrict__ W, unsigned short* __restrict__ WTb,
                           int K, int N) {
  __shared__ float s[32][33];
  const int tx = threadIdx.x & 31, ty = threadIdx.x >> 5;  // ty 0..7
  const int n0 = blockIdx.x * 32, k0 = blockIdx.y * 32;
#pragma unroll
  for (int j = 0; j < 4; ++j)
    s[ty + 8 * j][tx] = W[(size_t)(k0 + ty + 8 * j) * N + n0 + tx];
  __syncthreads();
#pragma unroll
  for (int j = 0; j < 4; ++j)
    WTb[(size_t)(n0 + ty + 8 * j) * K + k0 + tx] = f2bf(s[tx][ty + 8 * j]);
}

// ---------------- text projections: k (l2-normed, head-major), v, pad ---------
__global__ __launch_bounds__(256)
void text_proj_kernel(const float* __restrict__ text,
                      const float* __restrict__ wk, const float* __restrict__ bk,
                      const float* __restrict__ wv, const float* __restrict__ bv,
                      float* __restrict__ kh,   // [B,8,77,64] head-major
                      float* __restrict__ vf,   // [616,512]
                      float* __restrict__ pad) {
  __shared__ float st[512];
  __shared__ float red[8];
  const int tid = threadIdx.x;
  const int row = blockIdx.x;          // b*77 + t
  const int b = row / 77, t = row - b * 77;
  const int wvid = tid >> 6, lane = tid & 63;
  float t0 = text[(size_t)row * 512 + tid];
  float t1 = text[(size_t)row * 512 + tid + 256];
  st[tid] = t0;
  st[tid + 256] = t1;
  float ab = wred_sum(fabsf(t0) + fabsf(t1));
  if (lane == 0) red[wvid] = ab;
  __syncthreads();
  const int c0 = tid, c1 = tid + 256;
  float ak0 = bk[c0], ak1 = bk[c1];
  float av0 = bv[c0], av1 = bv[c1];
  for (int kk = 0; kk < 512; ++kk) {
    float tv = st[kk];
    ak0 = fmaf(tv, wk[(size_t)kk * 512 + c0], ak0);
    ak1 = fmaf(tv, wk[(size_t)kk * 512 + c1], ak1);
    av0 = fmaf(tv, wv[(size_t)kk * 512 + c0], av0);
    av1 = fmaf(tv, wv[(size_t)kk * 512 + c1], av1);
  }
  float ss = wred_sum(ak0 * ak0 + ak1 * ak1);
  if (lane == 0) red[4 + wvid] = ss;
  __syncthreads();
  float padsum = red[0] + red[1] + red[2] + red[3];
  float sstot = red[4] + red[5] + red[6] + red[7];
  float sc = 1.0f / fmaxf(sqrtf(sstot), 1e-6f);
  const int h0 = c0 >> 6, d0 = c0 & 63;
  const int h1 = c1 >> 6, d1 = c1 & 63;
  kh[(((size_t)b * 8 + h0) * 77 + t) * 64 + d0] = ak0 * sc;
  kh[(((size_t)b * 8 + h1) * 77 + t) * 64 + d1] = ak1 * sc;
  vf[(size_t)row * 512 + c0] = av0;
  vf[(size_t)row * 512 + c1] = av1;
  if (tid == 0) pad[row] = (padsum <= 1e-6f) ? 1.0f : 0.0f;
}

// ---------------- fused attention v2 ------------------------------------------
__device__ __forceinline__ void top3_insert(float v, float& a, float& b, float& c) {
  if (v > a) { c = b; b = a; a = v; }
  else if (v > b) { c = b; b = v; }
  else if (v > c) { c = v; }
}

__global__ __launch_bounds__(256)
void attn_kernel(const float* __restrict__ q,    // [32768,512] fp32 l2-normed
                 const float* __restrict__ kh,   // [B,8,77,64] head-major
                 const float* __restrict__ vf,   // [616,512]
                 const float* __restrict__ pad,  // [616]
                 const float* __restrict__ logit_scale,
                 unsigned short* __restrict__ alignedb,  // [32768,512] bf16
                 float* __restrict__ conf_out) {         // [32768]
  __shared__ __align__(16) float s_q[512];
  __shared__ float s_sim[8][80];
  __shared__ float s_lw[8][80];
  __shared__ int s_lt[8][80];
  __shared__ int s_cnt[8];
  __shared__ float s_conf[8];
  const int tid = threadIdx.x;
  const int row = blockIdx.x;
  const int b = row >> 12;
  const float ls = fminf(fmaxf(logit_scale[0], -2.0f), 2.0f);
  const float scale = expf(ls) * 0.125f;
  s_q[tid] = q[(size_t)row * 512 + tid];
  s_q[tid + 256] = q[(size_t)row * 512 + tid + 256];
  __syncthreads();
  const int wv = tid >> 6, lane = tid & 63;
  const int tc = lane >> 3, dc = lane & 7;
  // ---- sims: wave handles 2 heads; 8 t-values x 8 channel-chunks per pass ----
  for (int hh = 0; hh < 2; ++hh) {
    const int h = wv * 2 + hh;
    const float* khh = kh + ((size_t)(b * 8 + h) * 77) * 64;
    float4 q0 = *(const float4*)(s_q + h * 64 + dc * 8);
    float4 q1 = *(const float4*)(s_q + h * 64 + dc * 8 + 4);
#pragma unroll
    for (int tg = 0; tg < 10; ++tg) {
      const int t = tg * 8 + tc;
      const bool valid = (t < 77);
      float acc = 0.f;
      if (valid) {
        const float* kp = khh + (size_t)t * 64 + dc * 8;
        float4 k0v = *(const float4*)kp;
        float4 k1v = *(const float4*)(kp + 4);
        acc = q0.x * k0v.x + q0.y * k0v.y + q0.z * k0v.z + q0.w * k0v.w +
              q1.x * k1v.x + q1.y * k1v.y + q1.z * k1v.z + q1.w * k1v.w;
      }
      acc += __shfl_xor(acc, 1, 64);
      acc += __shfl_xor(acc, 2, 64);
      acc += __shfl_xor(acc, 4, 64);
      if (valid && dc == 0) {
        s_sim[h][t] = (pad[b * 77 + t] != 0.0f) ? -INFINITY : acc * scale;
      }
    }
  }
  __syncthreads();
  // ---- per-head top3 / softmax / conf / compact lists ----
  const unsigned long long lmask = (1ull << lane) - 1ull;
  for (int hh = 0; hh < 2; ++hh) {
    const int h = wv * 2 + hh;
    const float v0 = s_sim[h][lane];
    const float v1 = (lane < 13) ? s_sim[h][lane + 64] : -INFINITY;
    float a = -INFINITY, bt = -INFINITY, c = -INFINITY;
    top3_insert(v0, a, bt, c);
    top3_insert(v1, a, bt, c);
#pragma unroll
    for (int s = 32; s >= 1; s >>= 1) {
      float oa = __shfl_xor(a, s, 64);
      float ob = __shfl_xor(bt, s, 64);
      float oc = __shfl_xor(c, s, 64);
      top3_insert(oa, a, bt, c);
      top3_insert(ob, a, bt, c);
      top3_insert(oc, a, bt, c);
    }
    const float thr = c, m1 = a;
    float ev0 = 0.f, ev1 = 0.f;
    float s0 = 0.f, s1 = 0.f, cnt = 0.f;
    if (v0 >= thr) {
      float e = expf(v0 - m1);
      if (e > 0.f) { ev0 = e; s0 += e; s1 += e * (v0 - m1); cnt += 1.f; }
    }
    if (v1 >= thr) {
      float e = expf(v1 - m1);
      if (e > 0.f) { ev1 = e; s0 += e; s1 += e * (v1 - m1); cnt += 1.f; }
    }
    s0 = wred_sum(s0);
    s1 = wred_sum(s1);
    cnt = wred_sum(cnt);
    float attn0 = 0.f, attn1 = 0.f, conf_h = 0.f;
    if (cnt > 0.f) {
      const float inv = 1.0f / s0;
      attn0 = ev0 * inv;
      attn1 = ev1 * inv;
      const float maxp = inv;
      const float teff = fmaxf(cnt, 2.0f);
      float entn = (logf(s0) - s1 * inv) + (77.0f - cnt) * 1.8420681e-7f;
      const float ent = fmaxf(entn / logf(teff), 0.0f);
      conf_h = fminf(fmaxf(maxp * (1.0f - ent), 0.0f), 1.0f);
    }
    unsigned long long m0 = __ballot(attn0 != 0.0f);
    unsigned long long m1b = __ballot(attn1 != 0.0f);
    const int c0n = __popcll(m0);
    if (attn0 != 0.0f) {
      const int rk = __popcll(m0 & lmask);
      s_lt[h][rk] = lane;
      s_lw[h][rk] = attn0;
    }
    if (attn1 != 0.0f) {
      const int rk = c0n + __popcll(m1b & lmask);
      s_lt[h][rk] = lane + 64;
      s_lw[h][rk] = attn1;
    }
    if (lane == 0) {
      s_cnt[h] = c0n + __popcll(m1b);
      s_conf[h] = conf_h;
    }
  }
  __syncthreads();
  if (tid == 0) {
    float cm = 0.f;
#pragma unroll
    for (int h = 0; h < 8; ++h) cm += s_conf[h];
    cm *= 0.125f;
    cm = fminf(fmaxf(cm, 0.0f), 1.0f);
    conf_out[row] = 0.35f + 0.65f * cm;
  }
  // ---- sparse PV via compact lists ----
  for (int c = tid; c < 512; c += 256) {
    const int h = c >> 6;
    const int cnt = s_cnt[h];
    float acc = 0.f;
    for (int i = 0; i < cnt; ++i)
      acc = fmaf(s_lw[h][i], vf[(size_t)(b * 77 + s_lt[h][i]) * 512 + c], acc);
    alignedb[(size_t)row * 512 + c] = f2bf(acc);
  }
}

// ---------------- bf16 MFMA GEMM: out = epi(A[M,K] @ WT[N,K]^T + bias) --------
// EPI 0: +bias -> fp32
// EPI 1: (.)*e1f[row] -> fp32                         (wo * conf)
// EPI 2: bf2f(e0b[r,c]) + scf*sigmoid(.)*clip(e2f[r],.3,1)*e1f[r,c] -> fp32 (y)
// EPI 3: gelu(.) -> bf16
// EPI 4: e1f[r,c] + . -> fp32                         (ffn2 + residual)
template <int EPI>
__global__ __launch_bounds__(256)
void mfma_gemm(const unsigned short* __restrict__ A,
               const unsigned short* __restrict__ WT,
               const float* __restrict__ bias,
               void* __restrict__ outv, int M, int N, int K,
               const unsigned short* __restrict__ e0b,
               const float* __restrict__ e1f,
               const float* __restrict__ e2f,
               const float* __restrict__ scf) {
  __shared__ __align__(16) unsigned short As[128 * 32];
  __shared__ __align__(16) unsigned short Bs[128 * 32];
  const int tid = threadIdx.x;
  const int wid = tid >> 6, lane = tid & 63;
  const int wr = wid >> 1, wc = wid & 1;
  const int m16 = lane & 15, quad = lane >> 4;
  const int row0 = blockIdx.y * 128, col0 = blockIdx.x * 128;

  const floatx4 zero4 = {0.f, 0.f, 0.f, 0.f};
  floatx4 acc[4][4];
#pragma unroll
  for (int i = 0; i < 4; ++i)
#pragma unroll
    for (int j = 0; j < 4; ++j) acc[i][j] = zero4;

  const unsigned short* Ag = A + (size_t)(row0 + (tid >> 2)) * K + (tid & 3) * 8;
  const unsigned short* Bg = WT + (size_t)(col0 + (tid >> 2)) * K + (tid & 3) * 8;
  char* AsB = (char*)As + tid * 16;
  char* BsB = (char*)Bs + tid * 16;
  const unsigned short* aP = As + (wr * 64 + m16) * 32 + quad * 8;
  const unsigned short* bP = Bs + (wc * 64 + m16) * 32 + quad * 8;

  for (int k0 = 0; k0 < K; k0 += 32) {
    __syncthreads();
    __builtin_amdgcn_global_load_lds(GPTR(Ag + k0), LPTR(AsB), 16, 0, 0);
    __builtin_amdgcn_global_load_lds(GPTR(Ag + (size_t)64 * K + k0), LPTR(AsB + 4096), 16, 0, 0);
    __builtin_amdgcn_global_load_lds(GPTR(Bg + k0), LPTR(BsB), 16, 0, 0);
    __builtin_amdgcn_global_load_lds(GPTR(Bg + (size_t)64 * K + k0), LPTR(BsB + 4096), 16, 0, 0);
    __syncthreads();
    bf16x8 af[4], bfr[4];
#pragma unroll
    for (int i = 0; i < 4; ++i) {
      af[i] = *(const bf16x8*)(aP + i * 16 * 32);
      bfr[i] = *(const bf16x8*)(bP + i * 16 * 32);
    }
#pragma unroll
    for (int mi = 0; mi < 4; ++mi)
#pragma unroll
      for (int ni = 0; ni < 4; ++ni)
        acc[mi][ni] = __builtin_amdgcn_mfma_f32_16x16x32_bf16(af[mi], bfr[ni], acc[mi][ni], 0, 0, 0);
  }

  float* outf = (float*)outv;
  unsigned short* outb = (unsigned short*)outv;
  float bb[4];
#pragma unroll
  for (int ni = 0; ni < 4; ++ni) bb[ni] = bias[col0 + wc * 64 + ni * 16 + m16];
  const float alphav = (EPI == 2) ? scf[0] : 0.f;

#pragma unroll
  for (int mi = 0; mi < 4; ++mi) {
#pragma unroll
    for (int r = 0; r < 4; ++r) {
      const int row = row0 + wr * 64 + mi * 16 + quad * 4 + r;
      float rowscale = 1.f, geo = 0.f;
      if (EPI == 1) rowscale = e1f[row];
      if (EPI == 2) geo = fminf(fmaxf(e2f[row], 0.3f), 1.0f);
#pragma unroll
      for (int ni = 0; ni < 4; ++ni) {
        const int col = col0 + wc * 64 + ni * 16 + m16;
        const size_t idx = (size_t)row * N + col;
        float o = acc[mi][ni][r] + bb[ni];
        if (EPI == 0) {
          outf[idx] = o;
        } else if (EPI == 1) {
          outf[idx] = o * rowscale;
        } else if (EPI == 2) {
          const float x = bf2f(e0b[idx]);
          const float al = e1f[idx];
          const float sg = 1.0f / (1.0f + expf(-o));
          outf[idx] = x + alphav * sg * geo * al;
        } else if (EPI == 3) {
          const float g = 0.5f * o * (1.0f + erff(o * 0.70710678118654752f));
          outb[idx] = f2bf(g);
        } else {
          outf[idx] = o + e1f[idx];
        }
      }
    }
  }
}

extern "C" void kernel_launch(void* const* d_in, const int* in_sizes, int n_in,
                              void* d_out, int out_size, void* d_ws, size_t ws_size,
                              hipStream_t stream) {
  const float* visual = (const float*)d_in[0];
  const float* text   = (const float*)d_in[1];
  const float* geo    = (const float*)d_in[2];
  const float* ln1_w  = (const float*)d_in[3];
  const float* ln1_b  = (const float*)d_in[4];
  const float* wq     = (const float*)d_in[5];
  const float* bq     = (const float*)d_in[6];
  const float* wk     = (const float*)d_in[7];
  const float* bk     = (const float*)d_in[8];
  const float* wvw    = (const float*)d_in[9];
  const float* bv     = (const float*)d_in[10];
  const float* wo     = (const float*)d_in[11];
  const float* bo     = (const float*)d_in[12];
  const float* gate_w = (const float*)d_in[13];
  const float* gate_b = (const float*)d_in[14];
  const float* logit_scale = (const float*)d_in[15];
  const float* alpha  = (const float*)d_in[16];
  const float* ln2_w  = (const float*)d_in[17];
  const float* ln2_b  = (const float*)d_in[18];
  const float* ffn_w1 = (const float*)d_in[19];
  const float* ffn_b1 = (const float*)d_in[20];
  const float* ffn_w2 = (const float*)d_in[21];
  const float* ffn_b2 = (const float*)d_in[22];
  float* out = (float*)d_out;

  char* ws = (char*)d_ws;
  float* BUF1          = (float*)ws;                          // 64 MB: q -> alignedO -> GCH(bf16)
  float* BUF2          = (float*)(ws + 67108864);             // 64 MB: y
  unsigned short* Xb   = (unsigned short*)(ws + 134217728);   // 32 MB: x bf16 -> h bf16
  unsigned short* ALb  = (unsigned short*)(ws + 167772160);   // 32 MB: aligned bf16
  unsigned short* wqT  = (unsigned short*)(ws + 201326592);
  unsigned short* woT  = wqT + 262144;
  unsigned short* gateT = woT + 262144;
  unsigned short* w1T  = gateT + 262144;                      // [2048,512]
  unsigned short* w2T  = w1T + 1048576;                       // [512,2048]
  float* KH   = (float*)(ws + 207093760);                     // [8,8,77,64]
  float* VF   = (float*)(ws + 208355328);                     // [616,512]
  float* PAD  = (float*)(ws + 209616896);
  float* CONF = (float*)(ws + 209619360);

  // weight transposes -> bf16 [N,K]
  transpose_bf16_kernel<<<dim3(16, 16), 256, 0, stream>>>(wq, wqT, 512, 512);
  transpose_bf16_kernel<<<dim3(16, 16), 256, 0, stream>>>(wo, woT, 512, 512);
  transpose_bf16_kernel<<<dim3(16, 16), 256, 0, stream>>>(gate_w, gateT, 512, 512);
  transpose_bf16_kernel<<<dim3(64, 16), 256, 0, stream>>>(ffn_w1, w1T, 512, 2048);
  transpose_bf16_kernel<<<dim3(16, 64), 256, 0, stream>>>(ffn_w2, w2T, 2048, 512);

  // 1. x = LN1(visual) -> bf16
  ln_bf16_kernel<<<MTOT / 4, 256, 0, stream>>>(visual, ln1_w, ln1_b, Xb);
  // 2. text projections
  text_proj_kernel<<<8 * TT, 256, 0, stream>>>(text, wk, bk, wvw, bv, KH, VF, PAD);
  // 3. q = x @ wq + bq (fp32 out)
  mfma_gemm<0><<<dim3(4, 256), 256, 0, stream>>>(Xb, wqT, bq, BUF1, MTOT, 512, 512,
                                                 nullptr, nullptr, nullptr, nullptr);
  // 4. l2norm(q)
  l2norm_kernel<<<MTOT / 4, 256, 0, stream>>>(BUF1);
  // 5. attention -> ALb (bf16), CONF
  attn_kernel<<<MTOT, 256, 0, stream>>>(BUF1, KH, VF, PAD, logit_scale, ALb, CONF);
  // 6. alignedO = (aligned @ wo + bo) * conf -> BUF1 fp32
  mfma_gemm<1><<<dim3(4, 256), 256, 0, stream>>>(ALb, woT, bo, BUF1, MTOT, 512, 512,
                                                 nullptr, CONF, nullptr, nullptr);
  // 7. y = x + alpha*sigmoid(x@gate_w+gate_b)*geo*alignedO -> BUF2 fp32
  mfma_gemm<2><<<dim3(4, 256), 256, 0, stream>>>(Xb, gateT, gate_b, BUF2, MTOT, 512, 512,
                                                 Xb, BUF1, geo, alpha);
  // 8. h = LN2(y) -> Xb (bf16)
  ln_bf16_kernel<<<MTOT / 4, 256, 0, stream>>>(BUF2, ln2_w, ln2_b, Xb);
  // 9. FFN in 2 chunks of 16384 rows; GCH (bf16) overlays BUF1
  unsigned short* GCH = (unsigned short*)BUF1;
  for (int ch = 0; ch < 2; ++ch) {
    const size_t off = (size_t)ch * 16384;
    mfma_gemm<3><<<dim3(16, 128), 256, 0, stream>>>(Xb + off * 512, w1T, ffn_b1, GCH,
                                                    16384, 2048, 512,
                                                    nullptr, nullptr, nullptr, nullptr);
    mfma_gemm<4><<<dim3(4, 128), 256, 0, stream>>>(GCH, w2T, ffn_b2, out + off * 512,
                                                   16384, 512, 2048,
                                                   nullptr, BUF2 + off * 512, nullptr, nullptr);
  }
}